// Round 2
// baseline (181.088 us; speedup 1.0000x reference)
//
#include <hip/hip_runtime.h>

#define SAMPLES 128
#define HID 256
#define NEARV 0.1f
#define FARV 4.0f
#define DZ ((FARV - NEARV) / (SAMPLES - 1))
#define EPSV 1e-6f

typedef __attribute__((ext_vector_type(8))) short v8s;   // 8 x bf16
typedef __attribute__((ext_vector_type(4))) float v4f;   // 4 x fp32

__device__ __forceinline__ unsigned short f2b(float f) {
  union { float f; unsigned u; } v; v.f = f;
  return (unsigned short)((v.u + 0x7fffu + ((v.u >> 16) & 1u)) >> 16);  // RNE
}

#if __has_builtin(__builtin_amdgcn_cvt_pk_bf16_f32)
typedef __bf16 bf2 __attribute__((ext_vector_type(2)));
__device__ __forceinline__ unsigned pk2(float a, float b) {
  union { bf2 v; unsigned u; } c;
  c.v = __builtin_amdgcn_cvt_pk_bf16_f32(a, b);
  return c.u;
}
#else
__device__ __forceinline__ unsigned pk2(float a, float b) {
  return (unsigned)f2b(a) | ((unsigned)f2b(b) << 16);
}
#endif

// Swizzled LDS address for the 128x256 bf16 activation buffer.
// 16B chunk column XOR'd with (m & 15): b128 reads and b64 writes land
// <=2-way per bank (free, m136).
__device__ __forceinline__ int haddr(int m, int k) {
  return m * 256 + ((((k >> 3) ^ (m & 15)) << 3) | (k & 7));
}

// Pack W2 (fp32 [K=256][N=256]) into bf16 fragment-linear layout:
// chunk ((gnt*8 + kt)*4 + q)*16 + l16 holds W2[k=kt*32+q*8 .. +8)][n=gnt*16+l16].
// (A- and B-operand fragment layouts are identical, so this serves the
// swapped GEMM unchanged.)
__global__ void pack_w2(const float* __restrict__ W2, unsigned short* __restrict__ out) {
  int t = blockIdx.x * 256 + threadIdx.x;   // 0..8191
  int l16 = t & 15;
  int q   = (t >> 4) & 3;
  int kt  = (t >> 6) & 7;
  int gnt = t >> 9;
  int n  = gnt * 16 + l16;
  int k0 = kt * 32 + q * 8;
#pragma unroll
  for (int j = 0; j < 8; ++j) out[t * 8 + j] = f2b(W2[(k0 + j) * 256 + n]);
}

// Pack head weights [Wsig | Wrgb(:256) | zeros] (K=256, N=16) the same way.
__global__ void pack_head(const float* __restrict__ Wsig, const float* __restrict__ Wrgb,
                          unsigned short* __restrict__ out) {
  int t = blockIdx.x * 256 + threadIdx.x;   // 0..511
  if (t >= 512) return;
  int n = t & 15, q = (t >> 4) & 3, kt = t >> 6;
  int k0 = kt * 32 + q * 8;
#pragma unroll
  for (int j = 0; j < 8; ++j) {
    int k = k0 + j;
    float v = 0.f;
    if (n == 0)      v = Wsig[k];
    else if (n < 4)  v = Wrgb[k * 3 + (n - 1)];
    out[t * 8 + j] = f2b(v);
  }
}

// One block per ray: 1024 threads = 16 waves, M=128 samples.
// LDS 68KB -> 2 blocks/CU = 32 waves/CU (full wave cap); 64-VGPR budget.
__global__ __launch_bounds__(1024, 8) void render(
    const float* __restrict__ cam, const float* __restrict__ rayv,
    const float* __restrict__ W1, const float* __restrict__ b1,
    const float* __restrict__ b2, const float* __restrict__ bsig,
    const float* __restrict__ Wrgb, const float* __restrict__ brgb,
    const unsigned short* __restrict__ W2p, const unsigned short* __restrict__ Hdp,
    float* __restrict__ out) {
  __shared__ __align__(16) unsigned short smem[128 * 256 + 2048];  // 64KB act + 4KB head partials

  const int tid = threadIdx.x;
  const int ray = blockIdx.x;
  float* fbH = (float*)(smem + 128 * 256);   // [2][128][4] f32 head partials

  // ---- Layer 1: h1[m][n] = relu(pts[m] . W1[:,n] + b1[n]) -> LDS bf16 [m][k]
  {
    float rvx = rayv[ray * 3 + 0], rvy = rayv[ray * 3 + 1], rvz = rayv[ray * 3 + 2];
    float rn  = 1.0f / sqrtf(rvx * rvx + rvy * rvy + rvz * rvz);
    float rdx = rvx * rn, rdy = rvy * rn, rdz = rvz * rn;
    float cx = cam[ray * 3 + 0], cy = cam[ray * 3 + 1], cz = cam[ray * 3 + 2];

    int n4 = (tid & 63) * 4;     // 4 consecutive n per thread
    int m0 = tid >> 6;           // 0..15
    float4 wa = *(const float4*)(W1 + n4);
    float4 wb = *(const float4*)(W1 + 256 + n4);
    float4 wc = *(const float4*)(W1 + 512 + n4);
    float4 bb = *(const float4*)(b1 + n4);
#pragma unroll
    for (int r = 0; r < 8; ++r) {
      int m = m0 + r * 16;
      float z = NEARV + DZ * (float)m;
      float px = cx + rdx * z, py = cy + rdy * z, pz = cz + rdz * z;
      float v0 = fmaxf(bb.x + px * wa.x + py * wb.x + pz * wc.x, 0.f);
      float v1 = fmaxf(bb.y + px * wa.y + py * wb.y + pz * wc.y, 0.f);
      float v2 = fmaxf(bb.z + px * wa.z + py * wb.z + pz * wc.z, 0.f);
      float v3 = fmaxf(bb.w + px * wa.w + py * wb.w + pz * wc.w, 0.f);
      uint2 pk; pk.x = pk2(v0, v1); pk.y = pk2(v2, v3);
      *(uint2*)(smem + haddr(m, n4)) = pk;   // ds_write_b64
    }
  }
  __syncthreads();

  const int lane = tid & 63;
  const int wv   = tid >> 6;        // 0..15
  const int q    = lane >> 4;
  const int l16  = lane & 15;
  const int nW   = (wv & 7) * 32;   // 8-way N split (2 tiles each)
  const int mW   = (wv >> 3) * 64;  // 2-way M split (4 tiles each)

  // ---- Layer 2 GEMM (swapped): C'[n][m] = (W2^T) @ (h1^T), M=128 N=256 K=256
  // A-frag = W2p (l16 -> n), B-frag = h1 from LDS (l16 -> m).
  v4f acc[2][4];
#pragma unroll
  for (int i = 0; i < 2; ++i)
#pragma unroll
    for (int j = 0; j < 4; ++j) acc[i][j] = (v4f)(0.f);

  const v8s* Bp = (const v8s*)W2p;
#pragma unroll
  for (int kt = 0; kt < 8; ++kt) {
    int k0 = kt * 32 + q * 8;
    v8s a0 = Bp[((((nW >> 4) + 0) * 8 + kt) * 4 + q) * 16 + l16];  // coalesced 1KB/wave
    v8s a1 = Bp[((((nW >> 4) + 1) * 8 + kt) * 4 + q) * 16 + l16];
#pragma unroll
    for (int mt = 0; mt < 4; ++mt) {
      v8s b = *(const v8s*)(smem + haddr(mW + mt * 16 + l16, k0));  // ds_read_b128
      acc[0][mt] = __builtin_amdgcn_mfma_f32_16x16x32_bf16(a0, b, acc[0][mt], 0, 0, 0);
      acc[1][mt] = __builtin_amdgcn_mfma_f32_16x16x32_bf16(a1, b, acc[1][mt], 0, 0, 0);
    }
  }
  __syncthreads();   // all h1 reads done; smem reused for h2

  // ---- epilogue: lane holds C'[n = nW+nt*16+q*4+r][m = mW+mt*16+l16]
  // 4 consecutive n at fixed m -> packed b64 write into [m][n] layout.
#pragma unroll
  for (int nt = 0; nt < 2; ++nt) {
    int n0 = nW + nt * 16 + q * 4;
    float4 bias = *(const float4*)(b2 + n0);
#pragma unroll
    for (int mt = 0; mt < 4; ++mt) {
      int m = mW + mt * 16 + l16;
      float v0 = fmaxf(acc[nt][mt][0] + bias.x, 0.f);
      float v1 = fmaxf(acc[nt][mt][1] + bias.y, 0.f);
      float v2 = fmaxf(acc[nt][mt][2] + bias.z, 0.f);
      float v3 = fmaxf(acc[nt][mt][3] + bias.w, 0.f);
      uint2 pk; pk.x = pk2(v0, v1); pk.y = pk2(v2, v3);
      *(uint2*)(smem + haddr(m, n0)) = pk;
    }
  }
  __syncthreads();

  // ---- heads: o[m][c] = h2[m] . Hd[:,c], K split across wave halves
  {
    const int half = wv >> 3;          // k-half
    const int mrow = (wv & 7) * 16;    // 16 rows per wave
    const v8s* Hp = (const v8s*)Hdp;
    v4f hacc = (v4f)(0.f);
#pragma unroll
    for (int kl = 0; kl < 4; ++kl) {
      int kt = half * 4 + kl;
      v8s a = *(const v8s*)(smem + haddr(mrow + l16, kt * 32 + q * 8));
      v8s b = Hp[(kt * 4 + q) * 16 + l16];
      hacc = __builtin_amdgcn_mfma_f32_16x16x32_bf16(a, b, hacc, 0, 0, 0);
    }
    if (l16 < 4) {
#pragma unroll
      for (int r = 0; r < 4; ++r)
        fbH[half * 512 + (mrow + q * 4 + r) * 4 + l16] = hacc[r];
    }
  }
  __syncthreads();

  // ---- volume rendering tail: single wave, shuffle scan, no barriers
  if (tid < 64) {
    float rvx = rayv[ray * 3 + 0], rvy = rayv[ray * 3 + 1], rvz = rayv[ray * 3 + 2];
    float rn  = 1.0f / sqrtf(rvx * rvx + rvy * rvy + rvz * rvz);
    float rdx = rvx * rn, rdy = rvy * rn, rdz = rvz * rn;
    float dw0 = brgb[0] - (rdx * Wrgb[768] + rdy * Wrgb[771] + rdz * Wrgb[774]);
    float dw1 = brgb[1] - (rdx * Wrgb[769] + rdy * Wrgb[772] + rdz * Wrgb[775]);
    float dw2 = brgb[2] - (rdx * Wrgb[770] + rdy * Wrgb[773] + rdz * Wrgb[776]);
    float bs = bsig[0];

    int m0 = tid * 2, m1 = m0 + 1;
    float s0 = fmaxf(fbH[m0 * 4] + fbH[512 + m0 * 4] + bs, 0.f);
    float s1 = fmaxf(fbH[m1 * 4] + fbH[512 + m1 * 4] + bs, 0.f);
    float a0 = 1.0f - __expf(-s0 * DZ);
    float a1 = (m1 == SAMPLES - 1) ? 1.0f : (1.0f - __expf(-s1 * DZ));
    float v0 = 1.0f - a0 + EPSV;
    float v1 = 1.0f - a1 + EPSV;

    float P = v0 * v1;                       // pairwise product
#pragma unroll
    for (int d = 1; d < 64; d <<= 1) {       // inclusive scan (cumprod) over lanes
      float t = __shfl_up(P, d);
      if (tid >= d) P *= t;
    }
    float E = __shfl_up(P, 1);               // exclusive
    if (tid == 0) E = 1.0f;
    float w0 = a0 * E;
    float w1 = a1 * E * v0;

    float dwc[3] = {dw0, dw1, dw2};
    float res[3];
#pragma unroll
    for (int c = 0; c < 3; ++c) {
      float x0 = fbH[m0 * 4 + 1 + c] + fbH[512 + m0 * 4 + 1 + c] + dwc[c];
      float x1 = fbH[m1 * 4 + 1 + c] + fbH[512 + m1 * 4 + 1 + c] + dwc[c];
      float r0 = 1.0f / (1.0f + __expf(-x0));
      float r1 = 1.0f / (1.0f + __expf(-x1));
      float s = w0 * r0 + w1 * r1;
#pragma unroll
      for (int d = 32; d >= 1; d >>= 1) s += __shfl_xor(s, d);
      res[c] = s;
    }
    if (tid == 0) {
      out[ray * 3 + 0] = res[0];
      out[ray * 3 + 1] = res[1];
      out[ray * 3 + 2] = res[2];
    }
  }
}

extern "C" void kernel_launch(void* const* d_in, const int* in_sizes, int n_in,
                              void* d_out, int out_size, void* d_ws, size_t ws_size,
                              hipStream_t stream) {
  const float* cam  = (const float*)d_in[0];
  const float* rayv = (const float*)d_in[1];
  const float* W1   = (const float*)d_in[2];
  const float* b1   = (const float*)d_in[3];
  const float* W2   = (const float*)d_in[4];
  const float* b2   = (const float*)d_in[5];
  const float* Wsig = (const float*)d_in[6];
  const float* bsig = (const float*)d_in[7];
  const float* Wrgb = (const float*)d_in[8];
  const float* brgb = (const float*)d_in[9];
  float* out = (float*)d_out;

  unsigned short* W2p = (unsigned short*)d_ws;     // 256*256 bf16 = 128 KB
  unsigned short* Hdp = W2p + 256 * 256;           // 256*16 bf16 = 8 KB

  int R = in_sizes[0] / 3;                         // B*N rays (4096)

  pack_w2<<<32, 256, 0, stream>>>(W2, W2p);
  pack_head<<<2, 256, 0, stream>>>(Wsig, Wrgb, Hdp);
  render<<<R, 1024, 0, stream>>>(cam, rayv, W1, b1, b2, bsig, Wrgb, brgb, W2p, Hdp, out);
}